// Round 10
// baseline (137.044 us; speedup 1.0000x reference)
//
#include <hip/hip_runtime.h>
#include <hip/hip_fp16.h>

// ============================================================================
// JResCOPAttn  (B=1, L=1024, D=128, fp32)
//
//   a  = x@Wl.T+bl ; tx = x@Wl2.T+bl2
//   tm[l,m,d] = sum_e a[l,e]*a[m,e]*Wlo[d,e] + blo[d]
//   y[l,d]    = x[l,d] + sum_m mask[l,m]*tm[l,m,d]*tx[m,d]  -> LayerNorm_d
//
// Round 10 (rounds 8/9: time invariant at ~795 cyc/wave-iter, VALUBusy 40 /
// MfmaUtil 31 consistent with 2 waves/SIMD residency => arch VGPR 112 + ~16-24
// AGPR crosses the 128-reg occupancy step; bh fragments (64 VGPR) are the wall):
//   (a) K-SPLIT across waves: 8 waves = 2(l-half) x 2(d-half) x 2(k-half);
//       each wave holds only its K=64 slice: bh 32, al 8, am 16 regs.
//       Fold is linear in c => k-half waves fold partial c into separate
//       part slices (chunk*2+kh); finish sums 32 slices (same as round 9).
//   (b) __launch_bounds__(512,4): VGPR cap 128 -> 4 waves/SIMD resident.
//   (c) mask u64 bitmask split into two u32 halves, m-loop in two unrolled
//       32-iter halves (1-instr bit test).
// MFMA floor: 256 wave-iters/SIMD x 155 cyc = 16.5 us.
// ============================================================================

typedef _Float16 f16x8 __attribute__((ext_vector_type(8)));
typedef float    f32x4 __attribute__((ext_vector_type(4)));
typedef unsigned int       u32;
typedef unsigned long long u64;

#define LL   1024
#define DD   128
#define MCH  64            // m's per chunk
#define TPAD 66            // txt row pad (f16 elems)
#define EPSV 1e-5f

// ---------------------------------------------------------------------------
// prep: a_h = (f16)(x@Wl.T + bl) ; tx = x@Wl2.T + bl2 ; wh = (f16)Wlo
// grid (4,64) x 256 : bx in {0,1} -> a cols [bx*64,..) ; {2,3} -> tx cols
// ---------------------------------------------------------------------------
__global__ __launch_bounds__(256) void prep_kernel(
    const float* __restrict__ x,  const float* __restrict__ Wl,
    const float* __restrict__ bl, const float* __restrict__ Wlo,
    const float* __restrict__ Wl2,const float* __restrict__ bl2,
    _Float16* __restrict__ a_h, float* __restrict__ tx_out,
    _Float16* __restrict__ wh)
{
    __shared__ float xs[16*128];
    __shared__ float wsh[64*129];          // stride 129 dwords: conflict-free
    const int t  = threadIdx.x;
    const int bx = blockIdx.x;
    const int by = blockIdx.y;
    const int l0 = by*16;

    #pragma unroll
    for (int i = 0; i < 8; ++i) { int f = i*256 + t; xs[f] = x[l0*DD + f]; }
    const float* Wsrc = ((bx < 2) ? Wl : Wl2) + (bx & 1)*64*DD;
    #pragma unroll
    for (int i = 0; i < 32; ++i) {
        int f = i*256 + t; int r = f >> 7, k = f & 127;
        wsh[r*129 + k] = Wsrc[f];
    }
    __syncthreads();

    const int col  = t & 63;               // output column within 64-chunk
    const int lsub = t >> 6;               // 4-row l group
    const float4* X4 = (const float4*)xs;
    float acc0 = 0.f, acc1 = 0.f, acc2 = 0.f, acc3 = 0.f;
    #pragma unroll
    for (int k4 = 0; k4 < 32; ++k4) {
        const float* wp = wsh + col*129 + k4*4;
        float4 wv = {wp[0], wp[1], wp[2], wp[3]};   // banks col%32: 2-way max
        float4 x0 = X4[(lsub*4+0)*32 + k4];         // broadcast within wave
        float4 x1 = X4[(lsub*4+1)*32 + k4];
        float4 x2 = X4[(lsub*4+2)*32 + k4];
        float4 x3 = X4[(lsub*4+3)*32 + k4];
        acc0 += wv.x*x0.x + wv.y*x0.y + wv.z*x0.z + wv.w*x0.w;
        acc1 += wv.x*x1.x + wv.y*x1.y + wv.z*x1.z + wv.w*x1.w;
        acc2 += wv.x*x2.x + wv.y*x2.y + wv.z*x2.z + wv.w*x2.w;
        acc3 += wv.x*x3.x + wv.y*x3.y + wv.z*x3.z + wv.w*x3.w;
    }
    const int colg = (bx & 1)*64 + col;
    const float bv = ((bx < 2) ? bl : bl2)[colg];
    if (bx < 2) {
        a_h[(l0+lsub*4+0)*DD + colg] = (_Float16)(acc0 + bv);
        a_h[(l0+lsub*4+1)*DD + colg] = (_Float16)(acc1 + bv);
        a_h[(l0+lsub*4+2)*DD + colg] = (_Float16)(acc2 + bv);
        a_h[(l0+lsub*4+3)*DD + colg] = (_Float16)(acc3 + bv);
    } else {
        tx_out[(l0+lsub*4+0)*DD + colg] = acc0 + bv;
        tx_out[(l0+lsub*4+1)*DD + colg] = acc1 + bv;
        tx_out[(l0+lsub*4+2)*DD + colg] = acc2 + bv;
        tx_out[(l0+lsub*4+3)*DD + colg] = acc3 + bv;
    }

    const int gid = (by*4 + bx)*256 + t;   // Wlo -> f16, once
    if (gid < DD*DD) wh[gid] = (_Float16)Wlo[gid];
}

// ---------------------------------------------------------------------------
// one m-iteration (K=64 slice): A-build (4+4 pk_mul) -> 8 MFMA (C init=blov)
// -> masked fold.  Literal indices only after unroll (rule #20).
// MI is the bit index (0..31) into the u32 mask array WM.
// ---------------------------------------------------------------------------
#define COMPUTE(MI, AM, TV, WM)                                               \
  do {                                                                        \
    f16x8 ah_[2];                                                             \
    ah_[0] = al[0] * (AM)[0];                                                 \
    ah_[1] = al[1] * (AM)[1];                                                 \
    f32x4 c_[4];                                                              \
    _Pragma("unroll")                                                         \
    for (int nf_ = 0; nf_ < 4; ++nf_)                                         \
      c_[nf_] = f32x4{blov[nf_], blov[nf_], blov[nf_], blov[nf_]};            \
    _Pragma("unroll")                                                         \
    for (int kf_ = 0; kf_ < 2; ++kf_) {                                       \
      c_[0] = __builtin_amdgcn_mfma_f32_16x16x32_f16(ah_[kf_], bh[0][kf_], c_[0],0,0,0); \
      c_[1] = __builtin_amdgcn_mfma_f32_16x16x32_f16(ah_[kf_], bh[1][kf_], c_[1],0,0,0); \
      c_[2] = __builtin_amdgcn_mfma_f32_16x16x32_f16(ah_[kf_], bh[2][kf_], c_[2],0,0,0); \
      c_[3] = __builtin_amdgcn_mfma_f32_16x16x32_f16(ah_[kf_], bh[3][kf_], c_[3],0,0,0); \
    }                                                                         \
    _Pragma("unroll")                                                         \
    for (int r_ = 0; r_ < 4; ++r_) {                                          \
      const bool on_ = (((WM)[r_] >> (MI)) & 1u) != 0;                        \
      _Pragma("unroll")                                                       \
      for (int nf_ = 0; nf_ < 4; ++nf_)                                       \
        y[nf_][r_] = fmaf(on_ ? (TV)[nf_] : 0.0f, c_[nf_][r_], y[nf_][r_]);   \
    }                                                                         \
  } while (0)

// one 32-m half-loop using a u32 mask bank; MOFF in {0,32}
#define HALF_LOOP(WM, MOFF)                                                   \
  for (int ms = 0; ms < 32; ms += 2) {                                        \
    f16x8 am0[2], am1[2];                                                     \
    am0[0] = *(const f16x8*)(ash + (MOFF + ms)*DD     + kbase + 0*32 + grp*8);\
    am0[1] = *(const f16x8*)(ash + (MOFF + ms)*DD     + kbase + 1*32 + grp*8);\
    am1[0] = *(const f16x8*)(ash + (MOFF + ms + 1)*DD + kbase + 0*32 + grp*8);\
    am1[1] = *(const f16x8*)(ash + (MOFF + ms + 1)*DD + kbase + 1*32 + grp*8);\
    float tvA[4], tvB[4];                                                     \
    _Pragma("unroll")                                                         \
    for (int nf = 0; nf < 4; ++nf) {                                          \
      float2 f2 = __half22float2(                                             \
          *(const __half2*)(txt + (dbase + nf*16 + ln)*TPAD + MOFF + ms));    \
      tvA[nf] = f2.x; tvB[nf] = f2.y;                                         \
    }                                                                         \
    COMPUTE(ms,     am0, tvA, WM);                                            \
    COMPUTE(ms + 1, am1, tvB, WM);                                            \
  }

// ---------------------------------------------------------------------------
// heavy: block = (chunk: 64 m's) x (ltile: 32 l's) x all 128 d, 512 threads.
// 8 waves: wl = w>>2 (l-half), wd = (w>>1)&1 (d-half), kh = w&1 (K-half).
// Each wave: 16 l x 64 d x K=64 -> 8 MFMA/m-iter, bh only 32 VGPR.
// part slice = chunk*2 + kh (32 slices, f16) — finish sums 32 (as round 9).
// LDS = ash 16K + txt 16.9K + mbits 256B; 2 blocks/CU = 4 waves/SIMD.
// ---------------------------------------------------------------------------
__global__ __launch_bounds__(512, 4) void heavy_kernel(
    const _Float16* __restrict__ a_h, const float* __restrict__ tx,
    const _Float16* __restrict__ wh,  const int* __restrict__ mask,
    const float* __restrict__ blo,    _Float16* __restrict__ part)
{
    __shared__ __align__(16) _Float16 ash[MCH*DD];   // 16 KB, a m-rows
    __shared__ __align__(4)  _Float16 txt[DD*TPAD];  // 16.9 KB, tx^T padded
    __shared__ u64 mbits[32];                        // mask bits per l-row
    const int t     = threadIdx.x;                   // 0..511
    const int lane  = t & 63, w = t >> 6;            // 8 waves
    const int chunk = blockIdx.x;          // 0..15
    const int ltile = blockIdx.y;          // 0..31
    const int l0 = ltile*32, m0 = chunk*MCH;

    {   // ash: 16 KB = 1024 float4, 2/thread
        const float4* s4 = (const float4*)(a_h + m0*DD);
        float4* d4 = (float4*)ash;
        #pragma unroll
        for (int i = 0; i < 2; ++i) d4[i*512 + t] = s4[i*512 + t];
    }
    {   // txt[d][m] = (f16)tx[m0+m][d]
        #pragma unroll
        for (int i = 0; i < 4; ++i) {
            int idx = i*512 + t;           // 2048 float4 groups
            int m = idx >> 5, dg = idx & 31;
            float4 v = *(const float4*)(tx + (m0+m)*DD + dg*4);
            txt[(dg*4+0)*TPAD + m] = (_Float16)v.x;
            txt[(dg*4+1)*TPAD + m] = (_Float16)v.y;
            txt[(dg*4+2)*TPAD + m] = (_Float16)v.z;
            txt[(dg*4+3)*TPAD + m] = (_Float16)v.w;
        }
    }
    {   // mbits: each wave ballots one l-row's 64 m's per pass
        #pragma unroll
        for (int i = 0; i < 4; ++i) {
            int idx = i*512 + t;
            int row = idx >> 6, mcol = idx & 63;
            u64 b = __ballot(mask[(l0 + row)*LL + m0 + mcol] != 0);
            if ((t & 63) == 0) mbits[row] = b;
        }
    }
    __syncthreads();

    const int grp = lane >> 4, ln = lane & 15;
    const int wl = w >> 2, wd = (w >> 1) & 1, kh = w & 1;
    const int lbase = l0 + wl*16;          // this wave's 16 l rows
    const int dbase = wd*64;               // this wave's 64 d cols
    const int kbase = kh*64;               // this wave's K-half

    // B fragments: only this wave's K=64 slice -> 8 frags = 32 VGPR
    f16x8 bh[4][2];
    #pragma unroll
    for (int nf = 0; nf < 4; ++nf)
        #pragma unroll
        for (int kf = 0; kf < 2; ++kf)
            bh[nf][kf] = *(const f16x8*)(wh + (dbase + nf*16 + ln)*DD
                                            + kbase + kf*32 + grp*8);

    // this lane's a_l K-slice (A-frag row = lane&15 = l)
    f16x8 al[2];
    #pragma unroll
    for (int kf = 0; kf < 2; ++kf)
        al[kf] = *(const f16x8*)(a_h + (lbase + ln)*DD + kbase + kf*32 + grp*8);

    float blov[4];
    if (kh == 0) {   // blo folded once (k-half 0 only); k-half 1 gets C=0
        #pragma unroll
        for (int nf = 0; nf < 4; ++nf) blov[nf] = blo[dbase + nf*16 + ln];
    } else {
        #pragma unroll
        for (int nf = 0; nf < 4; ++nf) blov[nf] = 0.0f;
    }

    const int lrow0 = wl*16 + grp*4;       // local C-frag rows
    u32 wmbL[4], wmbH[4];
    #pragma unroll
    for (int r = 0; r < 4; ++r) {
        u64 b = mbits[lrow0 + r];
        wmbL[r] = (u32)b; wmbH[r] = (u32)(b >> 32);
    }

    f32x4 y[4] = {{0,0,0,0},{0,0,0,0},{0,0,0,0},{0,0,0,0}};

    HALF_LOOP(wmbL, 0);
    HALF_LOOP(wmbH, 32);

    // part[chunk*2+kh][l][d], f16 (k-half partials summed in finish)
    _Float16* dst = part + (size_t)(chunk*2 + kh)*(LL*DD);
    const int mrow0 = lbase + grp*4;
    #pragma unroll
    for (int nf = 0; nf < 4; ++nf)
        #pragma unroll
        for (int r = 0; r < 4; ++r)
            dst[(mrow0 + r)*DD + dbase + nf*16 + ln] = (_Float16)y[nf][r];
}

// ---------------------------------------------------------------------------
// finish: y = x + sum_32_slices part ; LayerNorm over d. grid 1024 x 128.
// ---------------------------------------------------------------------------
__global__ __launch_bounds__(128) void finish_kernel(
    const float* __restrict__ x, const _Float16* __restrict__ part,
    const float* __restrict__ gamma, const float* __restrict__ beta,
    float* __restrict__ out)
{
    const int l = blockIdx.x, t = threadIdx.x;
    float v = x[l*DD + t];
    #pragma unroll
    for (int ch = 0; ch < 32; ++ch)
        v += (float)part[((size_t)ch*LL + l)*DD + t];

    float s = v, s2 = v*v;
    #pragma unroll
    for (int o = 32; o > 0; o >>= 1) {     // wave64 butterfly
        s  += __shfl_xor(s, o);
        s2 += __shfl_xor(s2, o);
    }
    __shared__ float red[4];
    if ((t & 63) == 0) { red[(t>>6)*2+0] = s; red[(t>>6)*2+1] = s2; }
    __syncthreads();
    const float S  = red[0] + red[2];
    const float S2 = red[1] + red[3];
    const float mu  = S * (1.0f/128.0f);
    const float var = S2 * (1.0f/128.0f) - mu*mu;
    const float inv = rsqrtf(var + EPSV);
    out[l*DD + t] = (v - mu)*inv*gamma[t] + beta[t];
}

// ---------------------------------------------------------------------------
extern "C" void kernel_launch(void* const* d_in, const int* in_sizes, int n_in,
                              void* d_out, int out_size, void* d_ws, size_t ws_size,
                              hipStream_t stream)
{
    (void)in_sizes; (void)n_in; (void)out_size; (void)ws_size;
    const float* x     = (const float*)d_in[0];
    const int*   mask  = (const int*)  d_in[1];
    const float* Wl    = (const float*)d_in[2];
    const float* bl    = (const float*)d_in[3];
    const float* Wlo   = (const float*)d_in[4];
    const float* blo   = (const float*)d_in[5];
    const float* Wl2   = (const float*)d_in[6];
    const float* bl2   = (const float*)d_in[7];
    const float* gamma = (const float*)d_in[8];
    const float* beta  = (const float*)d_in[9];
    float* out = (float*)d_out;

    // ws layout (~9.4MB): a_h f16 256K | tx f32 512K | wh f16 32K | part f16 8.4M @1M
    char* ws = (char*)d_ws;
    _Float16* a_h  = (_Float16*)(ws);
    float*    tx_b = (float*)   (ws + (256u<<10));
    _Float16* wh   = (_Float16*)(ws + (768u<<10));
    _Float16* part = (_Float16*)(ws + (1024u<<10));

    prep_kernel  <<<dim3(4,64),  256, 0, stream>>>(x, Wl, bl, Wlo, Wl2, bl2,
                                                   a_h, tx_b, wh);
    heavy_kernel <<<dim3(16,32), 512, 0, stream>>>(a_h, tx_b, wh, mask, blo, part);
    finish_kernel<<<1024, 128, 0, stream>>>(x, part, gamma, beta, out);
}

// Round 11
// 129.102 us; speedup vs baseline: 1.0615x; 1.0615x over previous
//
#include <hip/hip_runtime.h>
#include <hip/hip_fp16.h>

// ============================================================================
// JResCOPAttn  (B=1, L=1024, D=128, fp32)
//
//   a  = x@Wl.T+bl ; tx = x@Wl2.T+bl2
//   tm[l,m,d] = sum_e a[l,e]*a[m,e]*Wlo[d,e] + blo[d]
//   y[l,d]    = x[l,d] + sum_m mask[l,m]*tm[l,m,d]*tx[m,d]  -> LayerNorm_d
//
// Round 11 (round-10: forced 4 waves/SIMD spilled again — unified VGPR+AGPR
// 128-reg cap < live set; rounds 8/9: fold's MFMA->VALU dependency + per-m
// C-init keep 2 lockstep waves at ~795 cyc/iter):
//   ALGEBRAIC RESTRUCTURE — fold into the MFMA:
//     y[l,d] = sum_m sum_e (mask[l,m]*P[l,m,e]) * (Wlo[d,e]*tx[m,d])
//              + blo[d] * sum_m mask[l,m]*tx[m,d]
//   * mask zeroes A-frag rows (16 cndmask/m); tx scales B-frags (32 pk_mul/m);
//     C accumulates ACROSS m -> no per-m C-init, no fold, no y regs, and no
//     MFMA-result->VALU dependency in the loop (accumulator chains run at
//     matrix-pipe throughput).
//   * blo term: S = mask@tx as 4 side-MFMAs per chunk (mask bits -> f16 A),
//     folded at the part-write.
//   * 8 waves = 2 l-half x 4 d-quarter; per wave 16l x 32d x K=128 = 8 MFMA/m.
//     Regs ~140 -> __launch_bounds__(512,2) (cap 256, NO forced occupancy).
//   MFMA floor: 256 wave-iters/SIMD x 155 cyc = 16.5 us.
// ============================================================================

typedef _Float16 f16x8 __attribute__((ext_vector_type(8)));
typedef _Float16 f16x2 __attribute__((ext_vector_type(2)));
typedef float    f32x4 __attribute__((ext_vector_type(4)));
typedef unsigned int       u32;
typedef unsigned long long u64;

#define LL   1024
#define DD   128
#define MCH  64            // m's per chunk
#define EPSV 1e-5f

// ---------------------------------------------------------------------------
// prep: a_h = (f16)(x@Wl.T + bl) ; tx = x@Wl2.T + bl2 ; wh = (f16)Wlo
// grid (4,64) x 256 : bx in {0,1} -> a cols [bx*64,..) ; {2,3} -> tx cols
// ---------------------------------------------------------------------------
__global__ __launch_bounds__(256) void prep_kernel(
    const float* __restrict__ x,  const float* __restrict__ Wl,
    const float* __restrict__ bl, const float* __restrict__ Wlo,
    const float* __restrict__ Wl2,const float* __restrict__ bl2,
    _Float16* __restrict__ a_h, float* __restrict__ tx_out,
    _Float16* __restrict__ wh)
{
    __shared__ float xs[16*128];
    __shared__ float wsh[64*129];          // stride 129 dwords: conflict-free
    const int t  = threadIdx.x;
    const int bx = blockIdx.x;
    const int by = blockIdx.y;
    const int l0 = by*16;

    #pragma unroll
    for (int i = 0; i < 8; ++i) { int f = i*256 + t; xs[f] = x[l0*DD + f]; }
    const float* Wsrc = ((bx < 2) ? Wl : Wl2) + (bx & 1)*64*DD;
    #pragma unroll
    for (int i = 0; i < 32; ++i) {
        int f = i*256 + t; int r = f >> 7, k = f & 127;
        wsh[r*129 + k] = Wsrc[f];
    }
    __syncthreads();

    const int col  = t & 63;               // output column within 64-chunk
    const int lsub = t >> 6;               // 4-row l group
    const float4* X4 = (const float4*)xs;
    float acc0 = 0.f, acc1 = 0.f, acc2 = 0.f, acc3 = 0.f;
    #pragma unroll
    for (int k4 = 0; k4 < 32; ++k4) {
        const float* wp = wsh + col*129 + k4*4;
        float4 wv = {wp[0], wp[1], wp[2], wp[3]};   // banks col%32: 2-way max
        float4 x0 = X4[(lsub*4+0)*32 + k4];         // broadcast within wave
        float4 x1 = X4[(lsub*4+1)*32 + k4];
        float4 x2 = X4[(lsub*4+2)*32 + k4];
        float4 x3 = X4[(lsub*4+3)*32 + k4];
        acc0 += wv.x*x0.x + wv.y*x0.y + wv.z*x0.z + wv.w*x0.w;
        acc1 += wv.x*x1.x + wv.y*x1.y + wv.z*x1.z + wv.w*x1.w;
        acc2 += wv.x*x2.x + wv.y*x2.y + wv.z*x2.z + wv.w*x2.w;
        acc3 += wv.x*x3.x + wv.y*x3.y + wv.z*x3.z + wv.w*x3.w;
    }
    const int colg = (bx & 1)*64 + col;
    const float bv = ((bx < 2) ? bl : bl2)[colg];
    if (bx < 2) {
        a_h[(l0+lsub*4+0)*DD + colg] = (_Float16)(acc0 + bv);
        a_h[(l0+lsub*4+1)*DD + colg] = (_Float16)(acc1 + bv);
        a_h[(l0+lsub*4+2)*DD + colg] = (_Float16)(acc2 + bv);
        a_h[(l0+lsub*4+3)*DD + colg] = (_Float16)(acc3 + bv);
    } else {
        tx_out[(l0+lsub*4+0)*DD + colg] = acc0 + bv;
        tx_out[(l0+lsub*4+1)*DD + colg] = acc1 + bv;
        tx_out[(l0+lsub*4+2)*DD + colg] = acc2 + bv;
        tx_out[(l0+lsub*4+3)*DD + colg] = acc3 + bv;
    }

    const int gid = (by*4 + bx)*256 + t;   // Wlo -> f16, once
    if (gid < DD*DD) wh[gid] = (_Float16)Wlo[gid];
}

// ---------------------------------------------------------------------------
// one m-iter: am reads -> ah = mask ? al*am : 0 -> bs = bh * splat(tx[m,d])
// -> 8 MFMAs accumulating into persistent c0/c1.  No MFMA->VALU dependency.
// MI: bit index into u32 WM; MOFF in {0,32}.
// ---------------------------------------------------------------------------
#define MITER(MI, WM, MOFF)                                                   \
  do {                                                                        \
    const int mg_ = (MOFF) + (MI);                                            \
    f16x8 am0_ = *(const f16x8*)(ash + mg_*DD + 0*32 + grp*8);                \
    f16x8 am1_ = *(const f16x8*)(ash + mg_*DD + 1*32 + grp*8);                \
    f16x8 am2_ = *(const f16x8*)(ash + mg_*DD + 2*32 + grp*8);                \
    f16x8 am3_ = *(const f16x8*)(ash + mg_*DD + 3*32 + grp*8);                \
    _Float16 h0_ = txf[mg_*DD + dbase + ln];                                  \
    _Float16 h1_ = txf[mg_*DD + dbase + 16 + ln];                             \
    const bool on_ = (((WM) >> (MI)) & 1u) != 0;                              \
    f16x8 z_ = {};                                                            \
    f16x8 ah0_ = on_ ? al[0]*am0_ : z_;                                       \
    f16x8 ah1_ = on_ ? al[1]*am1_ : z_;                                       \
    f16x8 ah2_ = on_ ? al[2]*am2_ : z_;                                       \
    f16x8 ah3_ = on_ ? al[3]*am3_ : z_;                                       \
    f16x8 s0_ = {h0_,h0_,h0_,h0_,h0_,h0_,h0_,h0_};                            \
    f16x8 s1_ = {h1_,h1_,h1_,h1_,h1_,h1_,h1_,h1_};                            \
    f16x8 b00_ = bh[0][0]*s0_, b01_ = bh[0][1]*s0_;                           \
    f16x8 b02_ = bh[0][2]*s0_, b03_ = bh[0][3]*s0_;                           \
    f16x8 b10_ = bh[1][0]*s1_, b11_ = bh[1][1]*s1_;                           \
    f16x8 b12_ = bh[1][2]*s1_, b13_ = bh[1][3]*s1_;                           \
    c0 = __builtin_amdgcn_mfma_f32_16x16x32_f16(ah0_, b00_, c0, 0,0,0);       \
    c1 = __builtin_amdgcn_mfma_f32_16x16x32_f16(ah0_, b10_, c1, 0,0,0);       \
    c0 = __builtin_amdgcn_mfma_f32_16x16x32_f16(ah1_, b01_, c0, 0,0,0);       \
    c1 = __builtin_amdgcn_mfma_f32_16x16x32_f16(ah1_, b11_, c1, 0,0,0);       \
    c0 = __builtin_amdgcn_mfma_f32_16x16x32_f16(ah2_, b02_, c0, 0,0,0);       \
    c1 = __builtin_amdgcn_mfma_f32_16x16x32_f16(ah2_, b12_, c1, 0,0,0);       \
    c0 = __builtin_amdgcn_mfma_f32_16x16x32_f16(ah3_, b03_, c0, 0,0,0);       \
    c1 = __builtin_amdgcn_mfma_f32_16x16x32_f16(ah3_, b13_, c1, 0,0,0);       \
  } while (0)

// ---------------------------------------------------------------------------
// heavy: block = (chunk: 64 m's) x (ltile: 32 l's) x all 128 d, 512 threads.
// 8 waves: wl = w>>2 (l-half), wq = w&3 (d-quarter). Wave: 16l x 32d x K=128.
// LDS = ash 16K + txf 16K + mbits 256B. part f16, 16 slices.
// ---------------------------------------------------------------------------
__global__ __launch_bounds__(512, 2) void heavy_kernel(
    const _Float16* __restrict__ a_h, const float* __restrict__ tx,
    const _Float16* __restrict__ wh,  const int* __restrict__ mask,
    const float* __restrict__ blo,    _Float16* __restrict__ part)
{
    __shared__ __align__(16) _Float16 ash[MCH*DD];   // 16 KB, a m-rows (f16)
    __shared__ __align__(16) _Float16 txf[MCH*DD];   // 16 KB, tx m-rows (f16)
    __shared__ u64 mbits[32];                        // mask bits per l-row
    const int t     = threadIdx.x;                   // 0..511
    const int lane  = t & 63, w = t >> 6;            // 8 waves
    const int chunk = blockIdx.x;          // 0..15
    const int ltile = blockIdx.y;          // 0..31
    const int l0 = ltile*32, m0 = chunk*MCH;

    {   // ash: 16 KB = 1024 float4, 2/thread
        const float4* s4 = (const float4*)(a_h + m0*DD);
        float4* d4 = (float4*)ash;
        #pragma unroll
        for (int i = 0; i < 2; ++i) d4[i*512 + t] = s4[i*512 + t];
    }
    {   // txf[m][d] = (f16)tx[m0+m][d]; row-major (same layout as ash)
        #pragma unroll
        for (int i = 0; i < 4; ++i) {
            int idx = i*512 + t;           // 2048 float4 groups
            int m = idx >> 5, dg = idx & 31;
            float4 v = *(const float4*)(tx + (m0+m)*DD + dg*4);
            f16x2 p0 = {(_Float16)v.x, (_Float16)v.y};
            f16x2 p1 = {(_Float16)v.z, (_Float16)v.w};
            *(f16x2*)(txf + m*DD + dg*4)     = p0;
            *(f16x2*)(txf + m*DD + dg*4 + 2) = p1;
        }
    }
    {   // mbits: each wave ballots one l-row's 64 m's per pass
        #pragma unroll
        for (int i = 0; i < 4; ++i) {
            int idx = i*512 + t;
            int row = idx >> 6, mcol = idx & 63;
            u64 b = __ballot(mask[(l0 + row)*LL + m0 + mcol] != 0);
            if ((t & 63) == 0) mbits[row] = b;
        }
    }
    __syncthreads();

    const int grp = lane >> 4, ln = lane & 15;
    const int wl = w >> 2, wq = w & 3;
    const int lbase = l0 + wl*16;          // this wave's 16 l rows
    const int dbase = wq*32;               // this wave's 32 d cols (2 n-frags)

    // B fragments (static Wlo): col=lane&15=d, k=(lane>>4)*8+j
    f16x8 bh[2][4];
    #pragma unroll
    for (int nf = 0; nf < 2; ++nf)
        #pragma unroll
        for (int kf = 0; kf < 4; ++kf)
            bh[nf][kf] = *(const f16x8*)(wh + (dbase + nf*16 + ln)*DD
                                            + kf*32 + grp*8);

    // this lane's a_l (A-frag row = lane&15 = l)
    f16x8 al[4];
    #pragma unroll
    for (int kf = 0; kf < 4; ++kf)
        al[kf] = *(const f16x8*)(a_h + (lbase + ln)*DD + kf*32 + grp*8);

    // per-lane mask word for OWN A-row l = lbase + ln
    const u64 mw = mbits[wl*16 + ln];
    const u32 mwL = (u32)mw, mwH = (u32)(mw >> 32);

    f32x4 c0 = {0,0,0,0}, c1 = {0,0,0,0};  // persistent accumulators (= y_raw)

    #pragma unroll 2
    for (int ms = 0; ms < 32; ++ms) MITER(ms, mwL, 0);
    #pragma unroll 2
    for (int ms = 0; ms < 32; ++ms) MITER(ms, mwH, 32);

    // ---- blo side-GEMM: S[l,d] = sum_m mask[l,m]*tx[m,d] (K = 64 m) ----
    f16x8 a2[2];                           // mask bits -> f16 0/1, k = m
    #pragma unroll
    for (int kf = 0; kf < 2; ++kf)
        #pragma unroll
        for (int j = 0; j < 8; ++j)
            a2[kf][j] = (_Float16)(int)((mw >> (kf*32 + grp*8 + j)) & 1ull);
    f16x8 b2[2][2];                        // tx, col=d, k=m (strided reads)
    #pragma unroll
    for (int nf = 0; nf < 2; ++nf)
        #pragma unroll
        for (int kf = 0; kf < 2; ++kf)
            #pragma unroll
            for (int j = 0; j < 8; ++j)
                b2[nf][kf][j] = txf[(kf*32 + grp*8 + j)*DD + dbase + nf*16 + ln];
    f32x4 s0 = {0,0,0,0}, s1 = {0,0,0,0};
    s0 = __builtin_amdgcn_mfma_f32_16x16x32_f16(a2[0], b2[0][0], s0, 0,0,0);
    s0 = __builtin_amdgcn_mfma_f32_16x16x32_f16(a2[1], b2[0][1], s0, 0,0,0);
    s1 = __builtin_amdgcn_mfma_f32_16x16x32_f16(a2[0], b2[1][0], s1, 0,0,0);
    s1 = __builtin_amdgcn_mfma_f32_16x16x32_f16(a2[1], b2[1][1], s1, 0,0,0);

    // part[chunk][l][d], f16 ; y = c + blo*S
    const float blov0 = blo[dbase + ln];
    const float blov1 = blo[dbase + 16 + ln];
    _Float16* dst = part + (size_t)chunk*(LL*DD);
    const int mrow0 = lbase + grp*4;       // C rows: (lane>>4)*4 + r
    #pragma unroll
    for (int r = 0; r < 4; ++r) {
        dst[(mrow0 + r)*DD + dbase + ln]      = (_Float16)fmaf(blov0, s0[r], c0[r]);
        dst[(mrow0 + r)*DD + dbase + 16 + ln] = (_Float16)fmaf(blov1, s1[r], c1[r]);
    }
}

// ---------------------------------------------------------------------------
// finish: y = x + sum_16_slices part ; LayerNorm over d. grid 1024 x 128.
// ---------------------------------------------------------------------------
__global__ __launch_bounds__(128) void finish_kernel(
    const float* __restrict__ x, const _Float16* __restrict__ part,
    const float* __restrict__ gamma, const float* __restrict__ beta,
    float* __restrict__ out)
{
    const int l = blockIdx.x, t = threadIdx.x;
    float v = x[l*DD + t];
    #pragma unroll
    for (int ch = 0; ch < 16; ++ch)
        v += (float)part[((size_t)ch*LL + l)*DD + t];

    float s = v, s2 = v*v;
    #pragma unroll
    for (int o = 32; o > 0; o >>= 1) {     // wave64 butterfly
        s  += __shfl_xor(s, o);
        s2 += __shfl_xor(s2, o);
    }
    __shared__ float red[4];
    if ((t & 63) == 0) { red[(t>>6)*2+0] = s; red[(t>>6)*2+1] = s2; }
    __syncthreads();
    const float S  = red[0] + red[2];
    const float S2 = red[1] + red[3];
    const float mu  = S * (1.0f/128.0f);
    const float var = S2 * (1.0f/128.0f) - mu*mu;
    const float inv = rsqrtf(var + EPSV);
    out[l*DD + t] = (v - mu)*inv*gamma[t] + beta[t];
}

// ---------------------------------------------------------------------------
extern "C" void kernel_launch(void* const* d_in, const int* in_sizes, int n_in,
                              void* d_out, int out_size, void* d_ws, size_t ws_size,
                              hipStream_t stream)
{
    (void)in_sizes; (void)n_in; (void)out_size; (void)ws_size;
    const float* x     = (const float*)d_in[0];
    const int*   mask  = (const int*)  d_in[1];
    const float* Wl    = (const float*)d_in[2];
    const float* bl    = (const float*)d_in[3];
    const float* Wlo   = (const float*)d_in[4];
    const float* blo   = (const float*)d_in[5];
    const float* Wl2   = (const float*)d_in[6];
    const float* bl2   = (const float*)d_in[7];
    const float* gamma = (const float*)d_in[8];
    const float* beta  = (const float*)d_in[9];
    float* out = (float*)d_out;

    // ws layout (~5.2MB): a_h f16 256K | tx f32 512K | wh f16 32K | part f16 4.2M @1M
    char* ws = (char*)d_ws;
    _Float16* a_h  = (_Float16*)(ws);
    float*    tx_b = (float*)   (ws + (256u<<10));
    _Float16* wh   = (_Float16*)(ws + (768u<<10));
    _Float16* part = (_Float16*)(ws + (1024u<<10));

    prep_kernel  <<<dim3(4,64),  256, 0, stream>>>(x, Wl, bl, Wlo, Wl2, bl2,
                                                   a_h, tx_b, wh);
    heavy_kernel <<<dim3(16,32), 512, 0, stream>>>(a_h, tx_b, wh, mask, blo, part);
    finish_kernel<<<1024, 128, 0, stream>>>(x, part, gamma, beta, out);
}